// Round 5
// baseline (92.485 us; speedup 1.0000x reference)
//
#include <hip/hip_runtime.h>
#include <math.h>

#define NC 14        // classes / centroids
#define BB 32        // batch
#define NN 16384     // subsampled points per batch
#define PP 4096      // origin points per batch
#define BLK_PER_B 8                    // distance slices per batch
#define NBLK (BB * BLK_PER_B)          // 256 blocks == 256 CUs
#define MAGIC 0x5F3C0D1Eu              // != 0xAAAAAAAA poison

// Single fused kernel. ws = NBLK uint64 slots: (MAGIC<<32) | float_bits(partial).
// No counter init needed: validity flag and value share one atomic 8B word,
// and 0xAA-poisoned slots can never spell MAGIC. Only block 0 waits (it polls
// slots after finishing its own work); every other block retires
// unconditionally -> deadlock-free with no co-residency assumption.
__global__ __launch_bounds__(256)
void fused_loss_kernel(const float* __restrict__ disp,   // [B,N]
                       const float* __restrict__ sub,    // [B,3,N]
                       const float* __restrict__ cpred,  // [B,3,C]
                       const float* __restrict__ origin, // [B,9,P]
                       const int*   __restrict__ target, // [B,P]
                       unsigned long long* __restrict__ slots,
                       float* __restrict__ out) {
    const int b    = blockIdx.x / BLK_PER_B;
    const int j    = blockIdx.x % BLK_PER_B;
    const int tid  = threadIdx.x;
    const int wave = tid >> 6;

    // ---- phase 1: per-batch centroids (redundant per block, wave-split LDS hist)
    __shared__ float s_hist[4][NC][4];   // [wave][class][x,y,z,count]
    for (int i = tid; i < 4 * NC * 4; i += 256) ((float*)s_hist)[i] = 0.f;
    __syncthreads();

    const float* ob = origin + (size_t)b * 9 * PP;
    const int*   tb = target + (size_t)b * PP;
    const int p0 = tid * 4;
    #pragma unroll
    for (int it = 0; it < PP / 1024; ++it) {       // 4 iterations, 16 pts/thread
        const int p = p0 + it * 1024;
        const int4   tv = *(const int4*)&tb[p];
        const float4 xv = *(const float4*)&ob[p];
        const float4 yv = *(const float4*)&ob[PP + p];
        const float4 zv = *(const float4*)&ob[2 * PP + p];
        const int   ts[4] = {tv.x, tv.y, tv.z, tv.w};
        const float xs[4] = {xv.x, xv.y, xv.z, xv.w};
        const float ys[4] = {yv.x, yv.y, yv.z, yv.w};
        const float zs[4] = {zv.x, zv.y, zv.z, zv.w};
        #pragma unroll
        for (int k = 0; k < 4; ++k) {
            float* h = s_hist[wave][ts[k]];
            atomicAdd(&h[0], xs[k]);
            atomicAdd(&h[1], ys[k]);
            atomicAdd(&h[2], zs[k]);
            atomicAdd(&h[3], 1.f);
        }
    }
    __syncthreads();

    __shared__ float s_cent[NC][3];
    if (tid < NC * 3) {
        int c = tid / 3, d = tid % 3;
        float s = s_hist[0][c][d] + s_hist[1][c][d] + s_hist[2][c][d] + s_hist[3][c][d];
        float n = s_hist[0][c][3] + s_hist[1][c][3] + s_hist[2][c][3] + s_hist[3][c][3];
        s_cent[c][d] = s / fmaxf(n, 1.f);
    }
    __syncthreads();

    // ---- phase 2: distance loss for this block's slice (8 pts/thread)
    const int n0 = j * (NN / BLK_PER_B) + tid * 4;   // slice of 2048, 2 f4 iters
    float sm = 0.f;
    #pragma unroll
    for (int it = 0; it < 2; ++it) {
        const int n = n0 + it * 1024;
        const float4 xv = *(const float4*)&sub[((size_t)b * 3 + 0) * NN + n];
        const float4 yv = *(const float4*)&sub[((size_t)b * 3 + 1) * NN + n];
        const float4 zv = *(const float4*)&sub[((size_t)b * 3 + 2) * NN + n];
        const float4 dv = *(const float4*)&disp[(size_t)b * NN + n];
        const float xs[4] = {xv.x, xv.y, xv.z, xv.w};
        const float ys[4] = {yv.x, yv.y, yv.z, yv.w};
        const float zs[4] = {zv.x, zv.y, zv.z, zv.w};
        const float ds[4] = {dv.x, dv.y, dv.z, dv.w};
        #pragma unroll
        for (int k = 0; k < 4; ++k) {
            float mn = 1e30f;
            #pragma unroll
            for (int c = 0; c < NC; ++c) {
                float dx = xs[k] - s_cent[c][0];
                float dy = ys[k] - s_cent[c][1];
                float dz = zs[k] - s_cent[c][2];
                mn = fminf(mn, dx * dx + dy * dy + dz * dz);
            }
            float v  = ds[k] - sqrtf(mn);
            float av = fabsf(v);
            sm += (av < 1.f) ? 0.5f * v * v : (av - 0.5f);
        }
    }
    #pragma unroll
    for (int o = 32; o > 0; o >>= 1) sm += __shfl_down(sm, o);

    __shared__ float s_part[4];
    if ((tid & 63) == 0) s_part[wave] = sm;

    // ---- phase 3: chamfer l1/l2 + separation (first block of each batch only)
    __shared__ float s_chamfer;
    if (j == 0) {
        __shared__ float s_D[NC][NC];
        if (tid < NC * NC) {
            int cp = tid / NC, c = tid % NC;
            float dx = cpred[(size_t)b * 3 * NC + 0 * NC + cp] - s_cent[c][0];
            float dy = cpred[(size_t)b * 3 * NC + 1 * NC + cp] - s_cent[c][1];
            float dz = cpred[(size_t)b * 3 * NC + 2 * NC + cp] - s_cent[c][2];
            s_D[cp][c] = dx * dx + dy * dy + dz * dz;
        }
        __syncthreads();
        __shared__ float s_contrib[NC];
        if (tid < NC) {
            float mn = s_D[0][tid];                  // l1: min over cp (column min)
            #pragma unroll
            for (int cp = 1; cp < NC; ++cp) mn = fminf(mn, s_D[cp][tid]);
            float m1 = 1e30f, m2 = 1e30f;            // row cp=tid: two smallest
            #pragma unroll
            for (int c = 0; c < NC; ++c) {
                float d = sqrtf(s_D[tid][c]);
                if (d < m1) { m2 = m1; m1 = d; }
                else if (d < m2) { m2 = d; }
            }
            s_contrib[tid] = mn + m1 * m1 + 0.1f * (m1 / m2);
        }
        __syncthreads();
        if (tid == 0) {
            float s = 0.f;
            #pragma unroll
            for (int c = 0; c < NC; ++c) s += s_contrib[c];
            s_chamfer = s;
        }
    } else if (tid == 0) {
        s_chamfer = 0.f;
    }
    __syncthreads();

    // ---- phase 4: publish this block's partial (value+flag in one atomic 8B)
    if (tid == 0) {
        float partial = s_part[0] + s_part[1] + s_part[2] + s_part[3] + s_chamfer;
        unsigned long long pack =
            ((unsigned long long)MAGIC << 32) | (unsigned long long)__float_as_uint(partial);
        __hip_atomic_store(&slots[blockIdx.x], pack,
                           __ATOMIC_RELAXED, __HIP_MEMORY_SCOPE_AGENT);
    }

    // ---- phase 5: block 0 gathers all partials and writes the scalar output
    if (blockIdx.x == 0) {
        float acc = 0.f;
        for (int i = tid; i < NBLK; i += 256) {      // 1 slot per thread
            unsigned long long v;
            do {
                v = __hip_atomic_load(&slots[i], __ATOMIC_RELAXED,
                                      __HIP_MEMORY_SCOPE_AGENT);
            } while ((unsigned)(v >> 32) != MAGIC);
            acc += __uint_as_float((unsigned)v);
        }
        #pragma unroll
        for (int o = 32; o > 0; o >>= 1) acc += __shfl_down(acc, o);
        __shared__ float s_fin[4];
        if ((tid & 63) == 0) s_fin[tid >> 6] = acc;
        __syncthreads();
        if (tid == 0) *out = s_fin[0] + s_fin[1] + s_fin[2] + s_fin[3];
    }
}

extern "C" void kernel_launch(void* const* d_in, const int* in_sizes, int n_in,
                              void* d_out, int out_size, void* d_ws, size_t ws_size,
                              hipStream_t stream) {
    const float* disp   = (const float*)d_in[0]; // [B,N]
    const float* sub    = (const float*)d_in[1]; // [B,3,N]
    const float* cpred  = (const float*)d_in[2]; // [B,3,C]
    const float* origin = (const float*)d_in[3]; // [B,9,P]
    const int*   target = (const int*)d_in[4];   // [B,P]

    fused_loss_kernel<<<NBLK, 256, 0, stream>>>(
        disp, sub, cpred, origin, target,
        (unsigned long long*)d_ws, (float*)d_out);
}

// Round 6
// 80.938 us; speedup vs baseline: 1.1427x; 1.1427x over previous
//
#include <hip/hip_runtime.h>
#include <math.h>

#define NC 14        // classes / centroids
#define BB 32        // batch
#define NN 16384     // subsampled points per batch
#define PP 4096      // origin points per batch

// ws layout (floats):
//   [0]               arrival counter (unsigned int)
//   [64 .. 64+256)    per-block partial (distance; +chamfer on first block/batch)
//   [640 .. 640+1344) centroids [B][C][3]
#define WS_COUNTER 0
#define WS_DIST    64
#define WS_CENT    640
#define BLK_PER_B  8                    // 8 distance blocks per batch
#define NBLK_B     (BB * BLK_PER_B)     // 256 blocks == 256 CUs

// Kernel A: one block per (batch, class). Each thread keeps just 4
// accumulators -> no spill. Block reduces and writes the centroid.
// Block 0 also zeroes the arrival counter (stream-ordered before kernel B).
__global__ void centroids_kernel(const float* __restrict__ origin, // [B,9,P]
                                 const int*   __restrict__ target, // [B,P]
                                 float* __restrict__ ws) {
    const int b    = blockIdx.x / NC;
    const int c    = blockIdx.x % NC;
    const int tid  = threadIdx.x;
    const int lane = tid & 63;
    const int wave = tid >> 6;

    if (blockIdx.x == 0 && tid == 0) ((unsigned int*)ws)[WS_COUNTER] = 0u;

    const float* ob = origin + (size_t)b * 9 * PP;
    const int*   tb = target + (size_t)b * PP;

    float sx = 0.f, sy = 0.f, sz = 0.f, cnt = 0.f;
    const int p0 = tid * 4;
    #pragma unroll
    for (int it = 0; it < PP / 1024; ++it) {   // 4 iterations, 16 pts/thread
        const int p = p0 + it * 1024;
        const int4   tv = *(const int4*)&tb[p];
        const float4 xv = *(const float4*)&ob[p];
        const float4 yv = *(const float4*)&ob[PP + p];
        const float4 zv = *(const float4*)&ob[2 * PP + p];
        float m0 = (tv.x == c) ? 1.f : 0.f;
        float m1 = (tv.y == c) ? 1.f : 0.f;
        float m2 = (tv.z == c) ? 1.f : 0.f;
        float m3 = (tv.w == c) ? 1.f : 0.f;
        sx = fmaf(m0, xv.x, fmaf(m1, xv.y, fmaf(m2, xv.z, fmaf(m3, xv.w, sx))));
        sy = fmaf(m0, yv.x, fmaf(m1, yv.y, fmaf(m2, yv.z, fmaf(m3, yv.w, sy))));
        sz = fmaf(m0, zv.x, fmaf(m1, zv.y, fmaf(m2, zv.z, fmaf(m3, zv.w, sz))));
        cnt += m0 + m1 + m2 + m3;
    }

    #pragma unroll
    for (int o = 32; o > 0; o >>= 1) {
        sx  += __shfl_down(sx, o);
        sy  += __shfl_down(sy, o);
        sz  += __shfl_down(sz, o);
        cnt += __shfl_down(cnt, o);
    }

    __shared__ float s_part[4][4];
    if (lane == 0) {
        s_part[wave][0] = sx; s_part[wave][1] = sy;
        s_part[wave][2] = sz; s_part[wave][3] = cnt;
    }
    __syncthreads();

    if (tid == 0) {
        float X = s_part[0][0] + s_part[1][0] + s_part[2][0] + s_part[3][0];
        float Y = s_part[0][1] + s_part[1][1] + s_part[2][1] + s_part[3][1];
        float Z = s_part[0][2] + s_part[1][2] + s_part[2][2] + s_part[3][2];
        float n = fmaxf(s_part[0][3] + s_part[1][3] + s_part[2][3] + s_part[3][3], 1.f);
        const int base = WS_CENT + (b * NC + c) * 3;
        ws[base + 0] = X / n;
        ws[base + 1] = Y / n;
        ws[base + 2] = Z / n;
    }
}

// Kernel B: distance loss (8 pts/thread, float4, 1 block/CU); first block of
// each batch also computes chamfer l1/l2 + separation; per-block partial ->
// slot; last-arriving block reduces 256 slots (one per thread) -> out.
__global__ void distance_loss_kernel(const float* __restrict__ disp,  // [B,N]
                                     const float* __restrict__ sub,   // [B,3,N]
                                     const float* __restrict__ cpred, // [B,3,C]
                                     float* __restrict__ ws,
                                     float* __restrict__ out) {
    const int b   = blockIdx.x / BLK_PER_B;
    const int j   = blockIdx.x % BLK_PER_B;
    const int tid = threadIdx.x;

    __shared__ float s_cent[NC * 3];
    if (tid < NC * 3)
        s_cent[tid] = ws[WS_CENT + (size_t)b * NC * 3 + tid];
    __syncthreads();

    const int n0 = j * (NN / BLK_PER_B) + tid * 4;   // slice of 2048
    float sm = 0.f;
    #pragma unroll
    for (int it = 0; it < 2; ++it) {
        const int n = n0 + it * 1024;
        const float4 xv = *(const float4*)&sub[((size_t)b * 3 + 0) * NN + n];
        const float4 yv = *(const float4*)&sub[((size_t)b * 3 + 1) * NN + n];
        const float4 zv = *(const float4*)&sub[((size_t)b * 3 + 2) * NN + n];
        const float4 dv = *(const float4*)&disp[(size_t)b * NN + n];
        const float xs[4] = {xv.x, xv.y, xv.z, xv.w};
        const float ys[4] = {yv.x, yv.y, yv.z, yv.w};
        const float zs[4] = {zv.x, zv.y, zv.z, zv.w};
        const float ds[4] = {dv.x, dv.y, dv.z, dv.w};
        #pragma unroll
        for (int k = 0; k < 4; ++k) {
            float mn = 1e30f;
            #pragma unroll
            for (int c = 0; c < NC; ++c) {
                float dx = xs[k] - s_cent[c * 3 + 0];
                float dy = ys[k] - s_cent[c * 3 + 1];
                float dz = zs[k] - s_cent[c * 3 + 2];
                mn = fminf(mn, dx * dx + dy * dy + dz * dz);
            }
            float v  = ds[k] - sqrtf(mn);
            float av = fabsf(v);
            sm += (av < 1.f) ? 0.5f * v * v : (av - 0.5f);
        }
    }

    #pragma unroll
    for (int o = 32; o > 0; o >>= 1) sm += __shfl_down(sm, o);

    __shared__ float s_part[4];
    const int wave = tid >> 6;
    if ((tid & 63) == 0) s_part[wave] = sm;

    // chamfer + separation: only on the first block of each batch
    __shared__ float s_chamfer;
    if (j == 0) {
        __shared__ float s_D[NC][NC];
        if (tid < NC * NC) {
            int cp = tid / NC, c = tid % NC;
            float dx = cpred[(size_t)b * 3 * NC + 0 * NC + cp] - s_cent[c * 3 + 0];
            float dy = cpred[(size_t)b * 3 * NC + 1 * NC + cp] - s_cent[c * 3 + 1];
            float dz = cpred[(size_t)b * 3 * NC + 2 * NC + cp] - s_cent[c * 3 + 2];
            s_D[cp][c] = dx * dx + dy * dy + dz * dz;
        }
        __syncthreads();
        __shared__ float s_contrib[NC];
        if (tid < NC) {
            float mn = s_D[0][tid];                  // l1: min over cp
            #pragma unroll
            for (int cp = 1; cp < NC; ++cp) mn = fminf(mn, s_D[cp][tid]);
            float m1 = 1e30f, m2 = 1e30f;            // row cp=tid: two smallest
            #pragma unroll
            for (int c = 0; c < NC; ++c) {
                float d = sqrtf(s_D[tid][c]);
                if (d < m1) { m2 = m1; m1 = d; }
                else if (d < m2) { m2 = d; }
            }
            s_contrib[tid] = mn + m1 * m1 + 0.1f * (m1 / m2);
        }
        __syncthreads();
        if (tid == 0) {
            float s = 0.f;
            #pragma unroll
            for (int c = 0; c < NC; ++c) s += s_contrib[c];
            s_chamfer = s;
        }
    } else if (tid == 0) {
        s_chamfer = 0.f;
    }
    __syncthreads();

    __shared__ unsigned int s_old;
    if (tid == 0) {
        ws[WS_DIST + blockIdx.x] =
            s_part[0] + s_part[1] + s_part[2] + s_part[3] + s_chamfer;
        __threadfence();
        s_old = atomicAdd((unsigned int*)ws + WS_COUNTER, 1u);
    }
    __syncthreads();

    if (s_old == NBLK_B - 1) {
        __threadfence();
        // exactly one slot per thread (NBLK_B == 256)
        float acc = __hip_atomic_load(&ws[WS_DIST + tid], __ATOMIC_RELAXED,
                                      __HIP_MEMORY_SCOPE_AGENT);
        #pragma unroll
        for (int o = 32; o > 0; o >>= 1) acc += __shfl_down(acc, o);
        __shared__ float s_fin[4];
        if ((tid & 63) == 0) s_fin[tid >> 6] = acc;
        __syncthreads();
        if (tid == 0)
            *out = s_fin[0] + s_fin[1] + s_fin[2] + s_fin[3];
    }
}

extern "C" void kernel_launch(void* const* d_in, const int* in_sizes, int n_in,
                              void* d_out, int out_size, void* d_ws, size_t ws_size,
                              hipStream_t stream) {
    const float* disp   = (const float*)d_in[0]; // [B,N]
    const float* sub    = (const float*)d_in[1]; // [B,3,N]
    const float* cpred  = (const float*)d_in[2]; // [B,3,C]
    const float* origin = (const float*)d_in[3]; // [B,9,P]
    const int*   target = (const int*)d_in[4];   // [B,P]

    float* out = (float*)d_out;
    float* ws  = (float*)d_ws;

    centroids_kernel<<<BB * NC, 256, 0, stream>>>(origin, target, ws);
    distance_loss_kernel<<<NBLK_B, 256, 0, stream>>>(disp, sub, cpred, ws, out);
}